// Round 2
// baseline (850.117 us; speedup 1.0000x reference)
//
#include <hip/hip_runtime.h>
#include <hip/hip_bf16.h>

// Sparse 3x3x3 conv (stride 1) via dense voxel grid.
//   G=256 per axis -> key = (x<<16)|(y<<8)|z addresses 2^24 cells.
//   Grid stores bf16 feature values; empty cell = 0x0000 = bf16(0), which
//   contributes W[k]*0 = 0, exactly matching the reference's `found` mask.
// Dtypes per reference: coords int32, feats/W/out float32. Grid is bf16
// (33.5 MB in d_ws) to halve footprint+traffic; fp32 accumulate keeps the
// rounding error (~0.013) well under the 0.0656 threshold.

#define GEXT 256u
#define GRID_CELLS (1u << 24)

__global__ void scatter_k(const int* __restrict__ coords,
                          const float* __restrict__ feats,
                          __hip_bfloat16* __restrict__ grid, int n) {
    int i = blockIdx.x * blockDim.x + threadIdx.x;
    if (i >= n) return;
    unsigned x = (unsigned)coords[3 * i + 0];
    unsigned y = (unsigned)coords[3 * i + 1];
    unsigned z = (unsigned)coords[3 * i + 2];
    unsigned key = (x << 16) | (y << 8) | z;
    grid[key] = __float2bfloat16(feats[i]);
}

__global__ void gather_k(const int* __restrict__ coords,
                         const __hip_bfloat16* __restrict__ grid,
                         const float* __restrict__ W,
                         float* __restrict__ out, int n) {
    __shared__ float sW[27];
    if (threadIdx.x < 27) sW[threadIdx.x] = W[threadIdx.x];
    __syncthreads();

    int i = blockIdx.x * blockDim.x + threadIdx.x;
    if (i >= n) return;
    int x = coords[3 * i + 0];
    int y = coords[3 * i + 1];
    int z = coords[3 * i + 2];

    float acc = 0.0f;
    int k = 0;
#pragma unroll
    for (int dx = -1; dx <= 1; ++dx) {
        int xx = x + dx;
        bool vx = (unsigned)xx < GEXT;
#pragma unroll
        for (int dy = -1; dy <= 1; ++dy) {
            int yy = y + dy;
            bool vxy = vx && ((unsigned)yy < GEXT);
            unsigned base = (((unsigned)xx & 255u) << 16) | (((unsigned)yy & 255u) << 8);
#pragma unroll
            for (int dz = -1; dz <= 1; ++dz, ++k) {
                int zz = z + dz;
                if (vxy && ((unsigned)zz < GEXT)) {
                    float f = __bfloat162float(grid[base | (unsigned)zz]);
                    acc += sW[k] * f;
                }
            }
        }
    }
    out[i] = acc;
}

extern "C" void kernel_launch(void* const* d_in, const int* in_sizes, int n_in,
                              void* d_out, int out_size, void* d_ws, size_t ws_size,
                              hipStream_t stream) {
    const int*   coords = (const int*)d_in[0];    // (N,3) int32
    const float* feats  = (const float*)d_in[1];  // (N,1) float32
    const float* W      = (const float*)d_in[2];  // (27,1,1) float32
    float*       out    = (float*)d_out;          // (N,1) float32

    int n = in_sizes[1];  // feats element count = N
    __hip_bfloat16* grid = (__hip_bfloat16*)d_ws;

    hipMemsetAsync(grid, 0, (size_t)GRID_CELLS * sizeof(__hip_bfloat16), stream);

    const int bs = 256;
    int nb = (n + bs - 1) / bs;
    scatter_k<<<nb, bs, 0, stream>>>(coords, feats, grid, n);
    gather_k<<<nb, bs, 0, stream>>>(coords, grid, W, out, n);
}

// Round 3
// 334.530 us; speedup vs baseline: 2.5412x; 2.5412x over previous
//
#include <hip/hip_runtime.h>
#include <hip/hip_bf16.h>

// Sparse 3x3x3 conv via DENSE grid-order convolution.
//   Round-2 lesson: per-voxel gather in random input order = 2.68 GB of L2
//   fill traffic (9 lines/voxel, zero reuse). Instead: scatter to a dense
//   bf16 grid, convolve the whole 256^3 grid in z-major coalesced order
//   (writes dense bf16 out-grid), then one random 2B read per voxel to
//   emit outputs in input order.
// d_ws layout: [0, 32MiB) bf16 in-grid, [32MiB, 64MiB) bf16 out-grid.

#define GEXT 256
#define GRID_CELLS (1u << 24)
#define GRID_BYTES ((size_t)GRID_CELLS * 2)

__global__ void scatter_k(const int* __restrict__ coords,
                          const float* __restrict__ feats,
                          __hip_bfloat16* __restrict__ grid, int n) {
    int i = blockIdx.x * blockDim.x + threadIdx.x;
    if (i >= n) return;
    unsigned x = (unsigned)coords[3 * i + 0];
    unsigned y = (unsigned)coords[3 * i + 1];
    unsigned z = (unsigned)coords[3 * i + 2];
    grid[(x << 16) | (y << 8) | z] = __float2bfloat16(feats[i]);
}

__global__ __launch_bounds__(256) void conv_k(const __hip_bfloat16* __restrict__ gin,
                                              const float* __restrict__ W,
                                              __hip_bfloat16* __restrict__ gout) {
    __shared__ float sW[27];
    if (threadIdx.x < 27) sW[threadIdx.x] = W[threadIdx.x];
    __syncthreads();

    int bid = blockIdx.x;          // 65536 blocks: one (x,y) z-row each
    int x = bid >> 8;
    int y = bid & 255;
    int z = threadIdx.x;

    float acc = 0.0f;
    int k = 0;
#pragma unroll
    for (int dx = -1; dx <= 1; ++dx) {
        int xx = x + dx;
        bool vx = (unsigned)xx < (unsigned)GEXT;
#pragma unroll
        for (int dy = -1; dy <= 1; ++dy) {
            int yy = y + dy;
            bool vxy = vx && ((unsigned)yy < (unsigned)GEXT);
            const __hip_bfloat16* row =
                gin + (((unsigned)(xx & 255) << 16) | ((unsigned)(yy & 255) << 8));
#pragma unroll
            for (int dz = -1; dz <= 1; ++dz, ++k) {
                int zz = z + dz;
                if (vxy && ((unsigned)zz < (unsigned)GEXT)) {
                    acc += sW[k] * __bfloat162float(row[zz]);
                }
            }
        }
    }
    gout[((unsigned)x << 16) | ((unsigned)y << 8) | (unsigned)z] = __float2bfloat16(acc);
}

__global__ void gather_out_k(const int* __restrict__ coords,
                             const __hip_bfloat16* __restrict__ gout,
                             float* __restrict__ out, int n) {
    int i = blockIdx.x * blockDim.x + threadIdx.x;
    if (i >= n) return;
    unsigned x = (unsigned)coords[3 * i + 0];
    unsigned y = (unsigned)coords[3 * i + 1];
    unsigned z = (unsigned)coords[3 * i + 2];
    out[i] = __bfloat162float(gout[(x << 16) | (y << 8) | z]);
}

extern "C" void kernel_launch(void* const* d_in, const int* in_sizes, int n_in,
                              void* d_out, int out_size, void* d_ws, size_t ws_size,
                              hipStream_t stream) {
    const int*   coords = (const int*)d_in[0];    // (N,3) int32
    const float* feats  = (const float*)d_in[1];  // (N,1) float32
    const float* W      = (const float*)d_in[2];  // (27,1,1) float32
    float*       out    = (float*)d_out;          // (N,1) float32

    int n = in_sizes[1];
    __hip_bfloat16* gin  = (__hip_bfloat16*)d_ws;
    __hip_bfloat16* gout = (__hip_bfloat16*)((char*)d_ws + GRID_BYTES);

    hipMemsetAsync(gin, 0, GRID_BYTES, stream);

    const int bs = 256;
    int nb = (n + bs - 1) / bs;
    scatter_k<<<nb, bs, 0, stream>>>(coords, feats, gin, n);
    conv_k<<<65536, 256, 0, stream>>>(gin, W, gout);
    gather_out_k<<<nb, bs, 0, stream>>>(coords, gout, out, n);
}

// Round 5
// 189.766 us; speedup vs baseline: 4.4798x; 1.7629x over previous
//
#include <hip/hip_runtime.h>
#include <hip/hip_bf16.h>

// Sparse 3x3x3 conv via dense grid, z-vectorized conv.
//   scatter -> dense bf16 in-grid; dense 3^3 conv in grid order (each thread
//   produces 8 consecutive z cells via ushort8 loads/stores); gather outputs
//   in input order.
// d_ws layout: [0, 32MiB) bf16 in-grid, [32MiB, 64MiB) bf16 out-grid.

#define GEXT 256
#define GRID_CELLS (1u << 24)
#define GRID_BYTES ((size_t)GRID_CELLS * 2)

typedef __attribute__((ext_vector_type(8))) unsigned short ushort8v;

__device__ __forceinline__ float bf16_to_f32(unsigned short b) {
    return __uint_as_float(((unsigned)b) << 16);
}
// RNE float->bf16 on raw bits (exact for finite values; inputs are finite).
__device__ __forceinline__ unsigned short f32_to_bf16(float f) {
    unsigned u = __float_as_uint(f);
    u += 0x7fffu + ((u >> 16) & 1u);
    return (unsigned short)(u >> 16);
}

__global__ void scatter_k(const int* __restrict__ coords,
                          const float* __restrict__ feats,
                          unsigned short* __restrict__ grid, int n) {
    int i = blockIdx.x * blockDim.x + threadIdx.x;
    if (i >= n) return;
    unsigned x = (unsigned)coords[3 * i + 0];
    unsigned y = (unsigned)coords[3 * i + 1];
    unsigned z = (unsigned)coords[3 * i + 2];
    grid[(x << 16) | (y << 8) | z] = f32_to_bf16(feats[i]);
}

// One block = one x-slice strip: 8 consecutive y rows x full z (2048 cells).
// Thread t: y = y0 + (t>>5), z segment [ (t&31)*8, +8 ).
__global__ __launch_bounds__(256) void conv_k(const unsigned short* __restrict__ gin,
                                              const float* __restrict__ W,
                                              unsigned short* __restrict__ gout) {
    __shared__ float sW[27];
    if (threadIdx.x < 27) sW[threadIdx.x] = W[threadIdx.x];
    __syncthreads();

    int bid = blockIdx.x;            // 8192 blocks = 256 x * 32 ygroups
    int x  = bid >> 5;
    int y  = (bid & 31) * 8 + (threadIdx.x >> 5);
    int z0 = (threadIdx.x & 31) * 8;

    float acc[8];
#pragma unroll
    for (int j = 0; j < 8; ++j) acc[j] = 0.0f;

#pragma unroll
    for (int dx = -1; dx <= 1; ++dx) {
        int xx = x + dx;
        if ((unsigned)xx >= (unsigned)GEXT) continue;   // wave-uniform
#pragma unroll
        for (int dy = -1; dy <= 1; ++dy) {
            int yy = y + dy;
            if ((unsigned)yy >= (unsigned)GEXT) continue;  // diverges only at y-edge blocks
            const unsigned short* row = gin + (((unsigned)xx << 16) | ((unsigned)yy << 8));

            // v[i] = in[z0-1+i], i=0..9 ; out-of-row z -> 0
            ushort8v mid = *(const ushort8v*)(row + z0);   // 16B aligned
            float v[10];
            v[0] = (z0 > 0)   ? bf16_to_f32(row[z0 - 1]) : 0.0f;
#pragma unroll
            for (int j = 0; j < 8; ++j) v[j + 1] = bf16_to_f32(mid[j]);
            v[9] = (z0 < 248) ? bf16_to_f32(row[z0 + 8]) : 0.0f;

            int kb = ((dx + 1) * 3 + (dy + 1)) * 3;        // base for dz=-1,0,1
            float w0 = sW[kb + 0], w1 = sW[kb + 1], w2 = sW[kb + 2];
#pragma unroll
            for (int j = 0; j < 8; ++j)
                acc[j] += w0 * v[j] + w1 * v[j + 1] + w2 * v[j + 2];
        }
    }

    ushort8v o;
#pragma unroll
    for (int j = 0; j < 8; ++j) o[j] = f32_to_bf16(acc[j]);
    *(ushort8v*)(gout + (((unsigned)x << 16) | ((unsigned)y << 8) | (unsigned)z0)) = o;
}

__global__ void gather_out_k(const int* __restrict__ coords,
                             const unsigned short* __restrict__ gout,
                             float* __restrict__ out, int n) {
    int i = blockIdx.x * blockDim.x + threadIdx.x;
    if (i >= n) return;
    unsigned x = (unsigned)coords[3 * i + 0];
    unsigned y = (unsigned)coords[3 * i + 1];
    unsigned z = (unsigned)coords[3 * i + 2];
    out[i] = bf16_to_f32(gout[(x << 16) | (y << 8) | z]);
}

extern "C" void kernel_launch(void* const* d_in, const int* in_sizes, int n_in,
                              void* d_out, int out_size, void* d_ws, size_t ws_size,
                              hipStream_t stream) {
    const int*   coords = (const int*)d_in[0];    // (N,3) int32
    const float* feats  = (const float*)d_in[1];  // (N,1) float32
    const float* W      = (const float*)d_in[2];  // (27,1,1) float32
    float*       out    = (float*)d_out;          // (N,1) float32

    int n = in_sizes[1];
    unsigned short* gin  = (unsigned short*)d_ws;
    unsigned short* gout = (unsigned short*)((char*)d_ws + GRID_BYTES);

    (void)hipMemsetAsync(gin, 0, GRID_BYTES, stream);

    const int bs = 256;
    int nb = (n + bs - 1) / bs;
    scatter_k<<<nb, bs, 0, stream>>>(coords, feats, gin, n);
    conv_k<<<8192, 256, 0, stream>>>(gin, W, gout);
    gather_out_k<<<nb, bs, 0, stream>>>(coords, gout, out, n);
}

// Round 6
// 179.163 us; speedup vs baseline: 4.7449x; 1.0592x over previous
//
#include <hip/hip_runtime.h>
#include <hip/hip_bf16.h>

// Sparse 3x3x3 conv via dense grid, fully fused routing.
//   scatter: gin[cell]=bf16(feat), idx[cell]=i+1  (0 = empty)
//   conv_out: dense z-vectorized 3^3 stencil (ushort8 loads, z-edges via
//             width-32 shuffles instead of scalar loads), writes out[idx-1]
//             directly -> no gather kernel, no gout grid.
// d_ws layout (fused): [0,32MiB) bf16 gin, [32MiB,96MiB) int32 idx.
// Fallback (ws_size < 96MiB): round-5 two-grid path with the shuffle conv.

#define GEXT 256
#define GRID_CELLS (1u << 24)
#define GIN_BYTES ((size_t)GRID_CELLS * 2)
#define IDX_BYTES ((size_t)GRID_CELLS * 4)

typedef __attribute__((ext_vector_type(8))) unsigned short ushort8v;
typedef __attribute__((ext_vector_type(4))) int int4v;

__device__ __forceinline__ float bf16_to_f32(unsigned short b) {
    return __uint_as_float(((unsigned)b) << 16);
}
// RNE float->bf16 on raw bits (exact for finite values).
__device__ __forceinline__ unsigned short f32_to_bf16(float f) {
    unsigned u = __float_as_uint(f);
    u += 0x7fffu + ((u >> 16) & 1u);
    return (unsigned short)(u >> 16);
}

__global__ void scatter_fused_k(const int* __restrict__ coords,
                                const float* __restrict__ feats,
                                unsigned short* __restrict__ gin,
                                int* __restrict__ idx, int n) {
    int i = blockIdx.x * blockDim.x + threadIdx.x;
    if (i >= n) return;
    unsigned x = (unsigned)coords[3 * i + 0];
    unsigned y = (unsigned)coords[3 * i + 1];
    unsigned z = (unsigned)coords[3 * i + 2];
    unsigned cell = (x << 16) | (y << 8) | z;
    gin[cell] = f32_to_bf16(feats[i]);
    idx[cell] = i + 1;
}

__global__ void scatter_k(const int* __restrict__ coords,
                          const float* __restrict__ feats,
                          unsigned short* __restrict__ gin, int n) {
    int i = blockIdx.x * blockDim.x + threadIdx.x;
    if (i >= n) return;
    unsigned x = (unsigned)coords[3 * i + 0];
    unsigned y = (unsigned)coords[3 * i + 1];
    unsigned z = (unsigned)coords[3 * i + 2];
    gin[(x << 16) | (y << 8) | z] = f32_to_bf16(feats[i]);
}

// 8-wide z stencil for cells [z0, z0+8) at (x,y). z-edge values come from
// neighbor lanes via width-32 shuffles (z-segments == 32-lane groups; the
// only divergent skips (y edges) are group-granular, so shuffles stay safe).
__device__ __forceinline__ void stencil8(const unsigned short* __restrict__ gin,
                                         const float* __restrict__ W,
                                         int x, int y, int z0, int lane,
                                         float acc[8]) {
#pragma unroll
    for (int j = 0; j < 8; ++j) acc[j] = 0.0f;
#pragma unroll
    for (int dx = -1; dx <= 1; ++dx) {
        int xx = x + dx;
        if ((unsigned)xx >= (unsigned)GEXT) continue;   // wave-uniform
#pragma unroll
        for (int dy = -1; dy <= 1; ++dy) {
            int yy = y + dy;
            if ((unsigned)yy >= (unsigned)GEXT) continue;  // 32-lane-group uniform
            const unsigned short* row =
                gin + (((unsigned)xx << 16) | ((unsigned)yy << 8));
            ushort8v mid = *(const ushort8v*)(row + z0);   // 16B aligned
            float v[10];
#pragma unroll
            for (int j = 0; j < 8; ++j) v[j + 1] = bf16_to_f32(mid[j]);
            float up = __shfl_up(v[8], 1, 32);    // lane l-1's in[z0-1]
            float dn = __shfl_down(v[1], 1, 32);  // lane l+1's in[z0+8]
            v[0] = (lane == 0)  ? 0.0f : up;      // z0==0   -> grid edge
            v[9] = (lane == 31) ? 0.0f : dn;      // z0==248 -> grid edge
            int kb = (dx + 1) * 9 + (dy + 1) * 3;
            float w0 = W[kb], w1 = W[kb + 1], w2 = W[kb + 2];  // scalar loads
#pragma unroll
            for (int j = 0; j < 8; ++j)
                acc[j] += w0 * v[j] + w1 * v[j + 1] + w2 * v[j + 2];
        }
    }
}

// Fused: one block = one x, 8 y rows, 32 z-segments. Routes results straight
// to out[] via the idx grid. No early exit: shuffles need all lanes live.
__global__ __launch_bounds__(256) void conv_out_k(const unsigned short* __restrict__ gin,
                                                  const int* __restrict__ idx,
                                                  const float* __restrict__ W,
                                                  float* __restrict__ out) {
    int bid = blockIdx.x;            // 8192 = 256 x * 32 ygroups
    int x  = bid >> 5;
    int y  = (bid & 31) * 8 + (threadIdx.x >> 5);
    int z0 = (threadIdx.x & 31) * 8;
    int lane = threadIdx.x & 31;

    unsigned c0 = ((unsigned)x << 16) | ((unsigned)y << 8) | (unsigned)z0;
    int4v i0 = *(const int4v*)(idx + c0);       // 32B-aligned dense read
    int4v i1 = *(const int4v*)(idx + c0 + 4);

    float acc[8];
    stencil8(gin, W, x, y, z0, lane, acc);

#pragma unroll
    for (int j = 0; j < 4; ++j)
        if (i0[j]) out[i0[j] - 1] = acc[j];
#pragma unroll
    for (int j = 0; j < 4; ++j)
        if (i1[j]) out[i1[j] - 1] = acc[j + 4];
}

// Fallback pair (ws too small for idx grid): conv->gout, then gather.
__global__ __launch_bounds__(256) void conv_gout_k(const unsigned short* __restrict__ gin,
                                                   const float* __restrict__ W,
                                                   unsigned short* __restrict__ gout) {
    int bid = blockIdx.x;
    int x  = bid >> 5;
    int y  = (bid & 31) * 8 + (threadIdx.x >> 5);
    int z0 = (threadIdx.x & 31) * 8;
    int lane = threadIdx.x & 31;

    float acc[8];
    stencil8(gin, W, x, y, z0, lane, acc);

    ushort8v o;
#pragma unroll
    for (int j = 0; j < 8; ++j) o[j] = f32_to_bf16(acc[j]);
    *(ushort8v*)(gout + (((unsigned)x << 16) | ((unsigned)y << 8) | (unsigned)z0)) = o;
}

__global__ void gather_out_k(const int* __restrict__ coords,
                             const unsigned short* __restrict__ gout,
                             float* __restrict__ out, int n) {
    int i = blockIdx.x * blockDim.x + threadIdx.x;
    if (i >= n) return;
    unsigned x = (unsigned)coords[3 * i + 0];
    unsigned y = (unsigned)coords[3 * i + 1];
    unsigned z = (unsigned)coords[3 * i + 2];
    out[i] = bf16_to_f32(gout[(x << 16) | (y << 8) | z]);
}

extern "C" void kernel_launch(void* const* d_in, const int* in_sizes, int n_in,
                              void* d_out, int out_size, void* d_ws, size_t ws_size,
                              hipStream_t stream) {
    const int*   coords = (const int*)d_in[0];    // (N,3) int32
    const float* feats  = (const float*)d_in[1];  // (N,1) float32
    const float* W      = (const float*)d_in[2];  // (27,1,1) float32
    float*       out    = (float*)d_out;          // (N,1) float32

    int n = in_sizes[1];
    unsigned short* gin = (unsigned short*)d_ws;

    const int bs = 256;
    int nb = (n + bs - 1) / bs;

    if (ws_size >= GIN_BYTES + IDX_BYTES) {
        int* idx = (int*)((char*)d_ws + GIN_BYTES);
        (void)hipMemsetAsync(d_ws, 0, GIN_BYTES + IDX_BYTES, stream);
        scatter_fused_k<<<nb, bs, 0, stream>>>(coords, feats, gin, idx, n);
        conv_out_k<<<8192, 256, 0, stream>>>(gin, idx, W, out);
    } else {
        unsigned short* gout = (unsigned short*)((char*)d_ws + GIN_BYTES);
        (void)hipMemsetAsync(gin, 0, GIN_BYTES, stream);
        scatter_k<<<nb, bs, 0, stream>>>(coords, feats, gin, n);
        conv_gout_k<<<8192, 256, 0, stream>>>(gin, W, gout);
        gather_out_k<<<nb, bs, 0, stream>>>(coords, gout, out, n);
    }
}

// Round 7
// 172.476 us; speedup vs baseline: 4.9289x; 1.0388x over previous
//
#include <hip/hip_runtime.h>
#include <hip/hip_bf16.h>

// Sparse 3x3x3 conv via dense grid, fused routing, no idx memset.
//   scatter: gin[cell]=bf16(feat) (never 0x0000 for real inputs), idx[cell]=i+1
//   conv_out: dense z-vectorized stencil, 2 y-rows per thread (rows shared
//             between the two accumulators), z-edges via width-32 shuffles.
//             Occupancy test = gin center bits != 0, so idx needs NO memset
//             (garbage idx is only read where gin==0 and never used).
// d_ws layout (fused): [0,32MiB) bf16 gin, [32MiB,96MiB) int32 idx.
// Fallback (ws_size < 96MiB): two-grid conv+gather path.

#define GEXT 256
#define GRID_CELLS (1u << 24)
#define GIN_BYTES ((size_t)GRID_CELLS * 2)
#define IDX_BYTES ((size_t)GRID_CELLS * 4)

typedef __attribute__((ext_vector_type(8))) unsigned short ushort8v;
typedef __attribute__((ext_vector_type(4))) int int4v;

__device__ __forceinline__ float bf16_to_f32(unsigned short b) {
    return __uint_as_float(((unsigned)b) << 16);
}
// RNE float->bf16 on raw bits (exact for finite values). Any normal f32
// maps to nonzero bf16 (same exponent range), so gin bits==0 <=> empty cell.
__device__ __forceinline__ unsigned short f32_to_bf16(float f) {
    unsigned u = __float_as_uint(f);
    u += 0x7fffu + ((u >> 16) & 1u);
    return (unsigned short)(u >> 16);
}

__global__ void scatter_fused_k(const int* __restrict__ coords,
                                const float* __restrict__ feats,
                                unsigned short* __restrict__ gin,
                                int* __restrict__ idx, int n) {
    int i = blockIdx.x * blockDim.x + threadIdx.x;
    if (i >= n) return;
    unsigned x = (unsigned)coords[3 * i + 0];
    unsigned y = (unsigned)coords[3 * i + 1];
    unsigned z = (unsigned)coords[3 * i + 2];
    unsigned cell = (x << 16) | (y << 8) | z;
    gin[cell] = f32_to_bf16(feats[i]);
    idx[cell] = i + 1;
}

__global__ void scatter_k(const int* __restrict__ coords,
                          const float* __restrict__ feats,
                          unsigned short* __restrict__ gin, int n) {
    int i = blockIdx.x * blockDim.x + threadIdx.x;
    if (i >= n) return;
    unsigned x = (unsigned)coords[3 * i + 0];
    unsigned y = (unsigned)coords[3 * i + 1];
    unsigned z = (unsigned)coords[3 * i + 2];
    gin[(x << 16) | (y << 8) | z] = f32_to_bf16(feats[i]);
}

// Load one gin row segment [z0-1, z0+8] as floats (z edges via width-32
// shuffles; lane==0/31 are the grid z-boundaries). Returns raw bits too.
__device__ __forceinline__ ushort8v load_row(const unsigned short* __restrict__ row,
                                             int z0, int lane, float v[10]) {
    ushort8v mid = *(const ushort8v*)(row + z0);   // 16B aligned
#pragma unroll
    for (int j = 0; j < 8; ++j) v[j + 1] = bf16_to_f32(mid[j]);
    float up = __shfl_up(v[8], 1, 32);
    float dn = __shfl_down(v[1], 1, 32);
    v[0] = (lane == 0)  ? 0.0f : up;
    v[9] = (lane == 31) ? 0.0f : dn;
    return mid;
}

__device__ __forceinline__ void fma_row(float acc[8], const float v[10],
                                        const float* __restrict__ W, int kb) {
    float w0 = W[kb], w1 = W[kb + 1], w2 = W[kb + 2];  // uniform scalar loads
#pragma unroll
    for (int j = 0; j < 8; ++j)
        acc[j] += w0 * v[j] + w1 * v[j + 1] + w2 * v[j + 2];
}

// Fused conv: one block = one x, 16 y rows (8 thread-ypairs), 32 z-segments.
// Thread owns rows (y0, y0+1) x 8 z cells; the 4 loaded rows per dx feed
// both accumulators. Routes results straight to out[] via idx, guarded by
// gin-center-bits occupancy.
__global__ __launch_bounds__(256) void conv_out_k(const unsigned short* __restrict__ gin,
                                                  const int* __restrict__ idx,
                                                  const float* __restrict__ W,
                                                  float* __restrict__ out) {
    int bid = blockIdx.x;            // 4096 = 256 x * 16 ygroups
    int x    = bid >> 4;
    int y0   = (bid & 15) * 16 + (threadIdx.x >> 5) * 2;
    int lane = threadIdx.x & 31;
    int z0   = lane * 8;

    float acc0[8], acc1[8];
#pragma unroll
    for (int j = 0; j < 8; ++j) { acc0[j] = 0.0f; acc1[j] = 0.0f; }

    ushort8v c0bits, c1bits;   // raw center bits (set on dx==0 pass, always valid rows)

#pragma unroll
    for (int dx = -1; dx <= 1; ++dx) {
        int xx = x + dx;
        if ((unsigned)xx >= (unsigned)GEXT) continue;   // wave-uniform
        const unsigned short* plane = gin + ((unsigned)xx << 16);
        float v[10];
        int kb = (dx + 1) * 9;

        // row y0-1 -> acc0 dy=-1
        if (y0 > 0) {                                    // 32-group uniform
            load_row(plane + ((unsigned)(y0 - 1) << 8), z0, lane, v);
            fma_row(acc0, v, W, kb + 0);
        }
        // row y0 -> acc0 dy=0, acc1 dy=-1
        {
            ushort8v m = load_row(plane + ((unsigned)y0 << 8), z0, lane, v);
            if (dx == 0) c0bits = m;
            fma_row(acc0, v, W, kb + 3);
            fma_row(acc1, v, W, kb + 0);
        }
        // row y0+1 -> acc0 dy=+1, acc1 dy=0
        {
            ushort8v m = load_row(plane + ((unsigned)(y0 + 1) << 8), z0, lane, v);
            if (dx == 0) c1bits = m;
            fma_row(acc0, v, W, kb + 6);
            fma_row(acc1, v, W, kb + 3);
        }
        // row y0+2 -> acc1 dy=+1
        if (y0 + 2 < GEXT) {                             // 32-group uniform
            load_row(plane + ((unsigned)(y0 + 2) << 8), z0, lane, v);
            fma_row(acc1, v, W, kb + 6);
        }
    }

    unsigned c0 = ((unsigned)x << 16) | ((unsigned)y0 << 8) | (unsigned)z0;
    int4v ia0 = *(const int4v*)(idx + c0);
    int4v ia1 = *(const int4v*)(idx + c0 + 4);
    int4v ib0 = *(const int4v*)(idx + c0 + 256);
    int4v ib1 = *(const int4v*)(idx + c0 + 260);

#pragma unroll
    for (int j = 0; j < 4; ++j) {
        if (c0bits[j])     out[ia0[j] - 1] = acc0[j];
        if (c0bits[j + 4]) out[ia1[j] - 1] = acc0[j + 4];
        if (c1bits[j])     out[ib0[j] - 1] = acc1[j];
        if (c1bits[j + 4]) out[ib1[j] - 1] = acc1[j + 4];
    }
}

// ---------- fallback path (ws too small for idx grid) ----------
__global__ __launch_bounds__(256) void conv_gout_k(const unsigned short* __restrict__ gin,
                                                   const float* __restrict__ W,
                                                   unsigned short* __restrict__ gout) {
    int bid = blockIdx.x;            // 8192 = 256 x * 32 ygroups
    int x    = bid >> 5;
    int y    = (bid & 31) * 8 + (threadIdx.x >> 5);
    int lane = threadIdx.x & 31;
    int z0   = lane * 8;

    float acc[8];
#pragma unroll
    for (int j = 0; j < 8; ++j) acc[j] = 0.0f;

#pragma unroll
    for (int dx = -1; dx <= 1; ++dx) {
        int xx = x + dx;
        if ((unsigned)xx >= (unsigned)GEXT) continue;
#pragma unroll
        for (int dy = -1; dy <= 1; ++dy) {
            int yy = y + dy;
            if ((unsigned)yy >= (unsigned)GEXT) continue;
            float v[10];
            load_row(gin + (((unsigned)xx << 16) | ((unsigned)yy << 8)), z0, lane, v);
            fma_row(acc, v, W, (dx + 1) * 9 + (dy + 1) * 3);
        }
    }
    ushort8v o;
#pragma unroll
    for (int j = 0; j < 8; ++j) o[j] = f32_to_bf16(acc[j]);
    *(ushort8v*)(gout + (((unsigned)x << 16) | ((unsigned)y << 8) | (unsigned)z0)) = o;
}

__global__ void gather_out_k(const int* __restrict__ coords,
                             const unsigned short* __restrict__ gout,
                             float* __restrict__ out, int n) {
    int i = blockIdx.x * blockDim.x + threadIdx.x;
    if (i >= n) return;
    unsigned x = (unsigned)coords[3 * i + 0];
    unsigned y = (unsigned)coords[3 * i + 1];
    unsigned z = (unsigned)coords[3 * i + 2];
    out[i] = bf16_to_f32(gout[(x << 16) | (y << 8) | z]);
}

extern "C" void kernel_launch(void* const* d_in, const int* in_sizes, int n_in,
                              void* d_out, int out_size, void* d_ws, size_t ws_size,
                              hipStream_t stream) {
    const int*   coords = (const int*)d_in[0];    // (N,3) int32
    const float* feats  = (const float*)d_in[1];  // (N,1) float32
    const float* W      = (const float*)d_in[2];  // (27,1,1) float32
    float*       out    = (float*)d_out;          // (N,1) float32

    int n = in_sizes[1];
    unsigned short* gin = (unsigned short*)d_ws;

    const int bs = 256;
    int nb = (n + bs - 1) / bs;

    if (ws_size >= GIN_BYTES + IDX_BYTES) {
        int* idx = (int*)((char*)d_ws + GIN_BYTES);
        (void)hipMemsetAsync(gin, 0, GIN_BYTES, stream);   // gin ONLY; idx needs no init
        scatter_fused_k<<<nb, bs, 0, stream>>>(coords, feats, gin, idx, n);
        conv_out_k<<<4096, 256, 0, stream>>>(gin, idx, W, out);
    } else {
        unsigned short* gout = (unsigned short*)((char*)d_ws + GIN_BYTES);
        (void)hipMemsetAsync(gin, 0, GIN_BYTES, stream);
        scatter_k<<<nb, bs, 0, stream>>>(coords, feats, gin, n);
        conv_gout_k<<<8192, 256, 0, stream>>>(gin, W, gout);
        gather_out_k<<<nb, bs, 0, stream>>>(coords, gout, out, n);
    }
}